// Round 10
// baseline (205.697 us; speedup 1.0000x reference)
//
#include <hip/hip_runtime.h>

// ---------------------------------------------------------------------------
// r[b,v] = sum_c (feats[b,c,v] - m[c,v]) / s[c,v] * weights[v,c] + bias[v]
// feats per scale k: GEMM  fmap_k (B*Ck x K=n^2)  @  prf_k^T (K x V)
// Fused epilogue: feats tile * w'[c,v]=weights[v,c]/s[c,v], c-reduced,
// atomicAdd into out (pre-initialized with off[v] = bias - sum m*w').
//
// R9 structure: ZERO-LDS direct-to-register GEMM. A fragments loaded
// straight from fp32 fmaps (lane-private rows, 16x128B coalesced segments,
// 8x L1/L2 reuse via quad-preserving XCD swizzle); B fragments from
// fragment-ordered bf16 ws images (L2-resident, zero-padded). No barriers,
// no gl_lds, no vmcnt drains -- each wave free-runs a pure dataflow loop.
// Ragged K-tails handled inline with guarded loads.
// ---------------------------------------------------------------------------

typedef float f32x4 __attribute__((ext_vector_type(4)));
typedef f32x4 __attribute__((aligned(4))) f32x4u;   // 4B-aligned vector load
typedef __bf16 bf16x8 __attribute__((ext_vector_type(8)));

#define V_DIM 512
#define C_TOT 960
#define B_DIM 128

#define NBT 268                  // B tiles: 4 col-groups x (49+13+4+1) steps
#define BT_TILE_E 8192           // 128 cols x 64 k, fragment-ordered
#define PREP_WP 1920
#define PREP_OFF 512
#define PREP_BLKS (NBT + PREP_WP + PREP_OFF)

#define GEMM_BLKS 5120           // 1024(s0)+1024(s1)+1024(s2)+2048(s3) = 8*640

// workspace layout (bytes): [wp][bt]
#define WP_BYTES 1966080L
#define BT_BYTES ((long)NBT * BT_TILE_E * 2)   // 4,390,912
#define WS_NEED  (WP_BYTES + BT_BYTES)

static __device__ __forceinline__ bf16x8 cvt8(f32x4 lo, f32x4 hi) {
  return bf16x8{(__bf16)lo[0], (__bf16)lo[1], (__bf16)lo[2], (__bf16)lo[3],
                (__bf16)hi[0], (__bf16)hi[1], (__bf16)hi[2], (__bf16)hi[3]};
}

template <bool BWS>
__global__ __launch_bounds__(256, 2)
void gemm_direct(const float* __restrict__ f0, const float* __restrict__ f1,
                 const float* __restrict__ f2, const float* __restrict__ f3,
                 const float* __restrict__ p0, const float* __restrict__ p1,
                 const float* __restrict__ p2, const float* __restrict__ p3,
                 const __bf16* __restrict__ bt,   // fragment-ordered B tiles
                 const float* __restrict__ weights,
                 const float* __restrict__ fs,
                 const float* __restrict__ wp,    // [C_TOT, V] or null
                 float* __restrict__ out)         // [B, V]
{
  const int tid  = threadIdx.x;
  const int lane = tid & 63;
  const int wid  = tid >> 6;
  const int wm   = wid >> 1;
  const int wn   = wid & 1;

  // bijective quad-preserving XCD swizzle (5120 = 8*640): the 4 N-sibling
  // blocks of one A-panel land on the same XCD -> A lines fetched once.
  const int bid   = blockIdx.x;
  const int sslot = bid >> 3;
  const int xcd   = bid & 7;
  const int w     = (((sslot >> 2) << 3) + xcd) * 4 + (sslot & 3);

  const float* fmap; const float* prf;
  int K, nst, bbase, Ck, Coff, y, bn_g, s0k, send;
  if (w < 1024) {
    fmap = f0; prf = p0; K = 3136; nst = 49; bbase = 0; Ck = 64; Coff = 0;
    bn_g = w & 3; y = (w >> 2) & 63;
    const int z = w >> 8; s0k = z * 12; send = (z == 3) ? 49 : s0k + 12;
  } else if (w < 2048) {
    const int l = w - 1024;
    fmap = f1; prf = p1; K = 784; nst = 13; bbase = 196; Ck = 128; Coff = 64;
    bn_g = l & 3; y = (l >> 2) & 127;
    const int z = l >> 9; s0k = z ? 7 : 0; send = z ? 13 : 7;
  } else if (w < 3072) {
    const int l = w - 2048;
    fmap = f2; prf = p2; K = 196; nst = 4; bbase = 248; Ck = 256; Coff = 192;
    bn_g = l & 3; y = l >> 2; s0k = 0; send = 4;
  } else {
    const int l = w - 3072;
    fmap = f3; prf = p3; K = 49; nst = 1; bbase = 264; Ck = 512; Coff = 448;
    bn_g = l & 3; y = l >> 2; s0k = 0; send = 1;
  }
  const long bm = (long)y * 128;
  const int  bn = bn_g * 128;

  f32x4 acc[4][4];
#pragma unroll
  for (int i = 0; i < 4; ++i)
#pragma unroll
    for (int j = 0; j < 4; ++j)
      acc[i][j] = f32x4{0.f, 0.f, 0.f, 0.f};

  const int la = lane & 15;            // fragment row-within-16
  const int kg = (lane >> 4) << 3;     // 8-elem k sub-offset: 0,8,16,24

  // per-i A row base pointers (lane-private rows)
  const float* arow[4];
#pragma unroll
  for (int i = 0; i < 4; ++i)
    arow[i] = fmap + (bm + wm * 64 + i * 16 + la) * (long)K;

  const __bf16* btbase = bt + (long)(bbase + bn_g * nst) * BT_TILE_E;
  const float* brow[4];
  if constexpr (!BWS) {
#pragma unroll
    for (int j = 0; j < 4; ++j)
      brow[j] = prf + (long)(bn + (wn * 4 + j) * 16 + la) * K;
  }

  const int kfull = K >> 6;                       // # full 64-wide steps
  const int send_full = send < kfull ? send : kfull;

  // ---------------- full steps: pure dataflow, no sync ----------------
  for (int ks = s0k; ks < send_full; ++ks) {
    bf16x8 bfr[8];
    if constexpr (BWS) {
      const __bf16* tbp = btbase + (long)ks * BT_TILE_E;
#pragma unroll
      for (int j = 0; j < 4; ++j)
#pragma unroll
        for (int kc = 0; kc < 2; ++kc)
          bfr[j * 2 + kc] = *(const bf16x8*)(
              tbp + ((((wn * 4 + j) * 2 + kc) << 6) + lane) * 8);
    } else {
#pragma unroll
      for (int j = 0; j < 4; ++j)
#pragma unroll
        for (int kc = 0; kc < 2; ++kc) {
          const float* p = brow[j] + ks * 64 + kc * 32 + kg;
          bfr[j * 2 + kc] = cvt8(*(const f32x4*)p, *(const f32x4*)(p + 4));
        }
    }
#pragma unroll
    for (int kc = 0; kc < 2; ++kc) {
      bf16x8 af[4];
#pragma unroll
      for (int i = 0; i < 4; ++i) {
        const float* p = arow[i] + ks * 64 + kc * 32 + kg;
        af[i] = cvt8(*(const f32x4*)p, *(const f32x4*)(p + 4));
      }
#pragma unroll
      for (int i = 0; i < 4; ++i)
#pragma unroll
        for (int j = 0; j < 4; ++j)
          acc[i][j] = __builtin_amdgcn_mfma_f32_16x16x32_bf16(
              af[i], bfr[j * 2 + kc], acc[i][j], 0, 0, 0);
    }
  }

  // ---------------- ragged last step (s1/s2/s3), guarded loads ----------
  if (send > send_full) {
    const int ks  = send_full;
    const int rem = K - ks * 64;       // 16 / 4 / 49
    bf16x8 bfr[8];
    if constexpr (BWS) {
      const __bf16* tbp = btbase + (long)ks * BT_TILE_E;   // zero-padded
#pragma unroll
      for (int j = 0; j < 4; ++j)
#pragma unroll
        for (int kc = 0; kc < 2; ++kc)
          bfr[j * 2 + kc] = *(const bf16x8*)(
              tbp + ((((wn * 4 + j) * 2 + kc) << 6) + lane) * 8);
    } else {
#pragma unroll
      for (int j = 0; j < 4; ++j)
#pragma unroll
        for (int kc = 0; kc < 2; ++kc) {
          const int k0 = kc * 32 + kg;
          const float* p = brow[j] + ks * 64 + k0;
          f32x4 lo = {0.f,0.f,0.f,0.f}, hi = {0.f,0.f,0.f,0.f};
          if (k0 + 8 <= rem) { lo = *(const f32x4u*)p; hi = *(const f32x4u*)(p + 4); }
          else {
#pragma unroll
            for (int e = 0; e < 4; ++e) if (k0 + e < rem)     lo[e] = p[e];
#pragma unroll
            for (int e = 0; e < 4; ++e) if (k0 + 4 + e < rem) hi[e] = p[4 + e];
          }
          bfr[j * 2 + kc] = cvt8(lo, hi);
        }
    }
#pragma unroll
    for (int kc = 0; kc < 2; ++kc) {
      bf16x8 af[4];
#pragma unroll
      for (int i = 0; i < 4; ++i) {
        const int k0 = kc * 32 + kg;
        const float* p = arow[i] + ks * 64 + k0;
        f32x4 lo = {0.f,0.f,0.f,0.f}, hi = {0.f,0.f,0.f,0.f};
        if (k0 + 8 <= rem) { lo = *(const f32x4u*)p; hi = *(const f32x4u*)(p + 4); }
        else {
#pragma unroll
          for (int e = 0; e < 4; ++e) if (k0 + e < rem)     lo[e] = p[e];
#pragma unroll
          for (int e = 0; e < 4; ++e) if (k0 + 4 + e < rem) hi[e] = p[4 + e];
        }
        af[i] = cvt8(lo, hi);
      }
#pragma unroll
      for (int i = 0; i < 4; ++i)
#pragma unroll
        for (int j = 0; j < 4; ++j)
          acc[i][j] = __builtin_amdgcn_mfma_f32_16x16x32_bf16(
              af[i], bfr[j * 2 + kc], acc[i][j], 0, 0, 0);
    }
  }

  // ---- epilogue: per-wave 64x64 feats sub-tile, c-reduce, atomicAdd.
  // C/D layout: frag row = (lane>>4)*4 + reg, frag col = lane&15   [m89]
  const long mbase = bm + wm * 64;
  const int  bidx  = (int)(mbase / Ck);
  const int  cbase = (int)(mbase % Ck) + Coff;
  const int  lrow  = ((lane >> 4) << 2);
  const int  lcol  = lane & 15;

#pragma unroll
  for (int j = 0; j < 4; ++j) {
    const int v = bn + wn * 64 + j * 16 + lcol;
    float s = 0.f;
#pragma unroll
    for (int i = 0; i < 4; ++i) {
      const int cg = cbase + i * 16 + lrow;
#pragma unroll
      for (int r = 0; r < 4; ++r) {
        float wfac;
        if (wp)  wfac = wp[(long)(cg + r) * V_DIM + v];
        else     wfac = weights[(long)v * C_TOT + cg + r]
                        / fs[(long)(cg + r) * V_DIM + v];
        s += acc[i][j][r] * wfac;
      }
    }
    s += __shfl_xor(s, 16);
    s += __shfl_xor(s, 32);
    if (lane < 16)
      atomicAdd(&out[(long)bidx * V_DIM + v], s);
  }
}

// ---------------------------------------------------------------------------
// One prep launch: [0,268) B -> fragment-ordered bf16 tiles (zero-padded);
// [268,2188) w'; [2188,2700) out init with the constant term.
// B tile layout: tile[(fj*2+kc)*64 + l)*8 + e] =
//   B[g*128 + fj*16 + (l&15), ks*64 + kc*32 + ((l>>4)<<3) + e]
// ---------------------------------------------------------------------------
__global__ void prep_all(const float* __restrict__ p0, const float* __restrict__ p1,
                         const float* __restrict__ p2, const float* __restrict__ p3,
                         const float* __restrict__ weights,
                         const float* __restrict__ bias,
                         const float* __restrict__ fm,
                         const float* __restrict__ fs,
                         float* __restrict__ wp,      // may be null
                         __bf16* __restrict__ bt,     // may be null
                         float* __restrict__ out)
{
  __shared__ float red[4];
  const int blk = blockIdx.x;
  const int tid = threadIdx.x;

  if (blk < NBT) {
    if (!bt) return;
    int t = blk; const float* src; int K, g, ks;
    if (t < 196)      { src = p0; K = 3136; g = t / 49; ks = t % 49; }
    else if (t < 248) { t -= 196; src = p1; K = 784; g = t / 13; ks = t % 13; }
    else if (t < 264) { t -= 248; src = p2; K = 196; g = t / 4;  ks = t % 4; }
    else              { t -= 264; src = p3; K = 49;  g = t;      ks = 0; }
    __bf16* dst = bt + (long)blk * BT_TILE_E;
#pragma unroll
    for (int it = 0; it < 4; ++it) {
      const int c2 = tid + it * 256;        // 0..1023 output 8-elem units
      const int fj = c2 >> 7;               // fragment col-group 0..7
      const int kc = (c2 >> 6) & 1;
      const int l  = c2 & 63;
      const int row  = g * 128 + fj * 16 + (l & 15);
      const int kcol = ks * 64 + kc * 32 + ((l >> 4) << 3);
      const float* sp = src + (long)row * K + kcol;
      bf16x8 h;
      if (kcol + 8 <= K) {
        h = cvt8(*(const f32x4u*)sp, *(const f32x4u*)(sp + 4));
      } else {
#pragma unroll
        for (int e = 0; e < 8; ++e)
          h[e] = (__bf16)((kcol + e < K) ? sp[e] : 0.f);
      }
      *(bf16x8*)&dst[(long)c2 * 8] = h;
    }
  } else if (blk < NBT + PREP_WP) {
    if (!wp) return;
    const int idx = (blk - NBT) * 256 + tid;   // exactly 960*512
    const int c = idx >> 9;
    const int v = idx & (V_DIM - 1);
    wp[idx] = weights[(long)v * C_TOT + c] / fs[idx];
  } else {
    const int v = blk - (NBT + PREP_WP);       // 0..511
    float s = 0.f;
    for (int c = tid; c < C_TOT; c += 256) {
      const long i = (long)c * V_DIM + v;
      s += fm[i] * weights[(long)v * C_TOT + c] / fs[i];
    }
#pragma unroll
    for (int o = 32; o; o >>= 1) s += __shfl_down(s, o);
    if ((tid & 63) == 0) red[tid >> 6] = s;
    __syncthreads();
    if (tid < B_DIM) {
      const float off = bias[v] - (red[0] + red[1] + red[2] + red[3]);
      out[(long)tid * V_DIM + v] = off;
    }
  }
}

extern "C" void kernel_launch(void* const* d_in, const int* in_sizes, int n_in,
                              void* d_out, int out_size, void* d_ws, size_t ws_size,
                              hipStream_t stream)
{
  const float* fmap0   = (const float*)d_in[0];
  const float* prf0    = (const float*)d_in[1];
  const float* fmap1   = (const float*)d_in[2];
  const float* prf1    = (const float*)d_in[3];
  const float* fmap2   = (const float*)d_in[4];
  const float* prf2    = (const float*)d_in[5];
  const float* fmap3   = (const float*)d_in[6];
  const float* prf3    = (const float*)d_in[7];
  const float* weights = (const float*)d_in[8];
  const float* bias    = (const float*)d_in[9];
  const float* fm      = (const float*)d_in[10];
  const float* fs      = (const float*)d_in[11];
  float* out = (float*)d_out;

  const bool has_wp = ws_size >= (size_t)WP_BYTES;
  const bool has_b  = ws_size >= (size_t)WS_NEED;
  float*  wp = has_wp ? (float*)d_ws : nullptr;
  __bf16* bt = has_b ? (__bf16*)((char*)d_ws + WP_BYTES) : nullptr;

  // 1) prep: B fragment tiles + w' + out init
  prep_all<<<dim3(PREP_BLKS), dim3(256), 0, stream>>>(
      prf0, prf1, prf2, prf3, weights, bias, fm, fs, wp, bt, out);

  // 2) single zero-LDS GEMM+readout launch over all 4 scales
  if (has_b) {
    gemm_direct<true><<<dim3(GEMM_BLKS), dim3(256), 0, stream>>>(
        fmap0, fmap1, fmap2, fmap3, prf0, prf1, prf2, prf3,
        bt, weights, fs, wp, out);
  } else {
    gemm_direct<false><<<dim3(GEMM_BLKS), dim3(256), 0, stream>>>(
        fmap0, fmap1, fmap2, fmap3, prf0, prf1, prf2, prf3,
        nullptr, weights, fs, wp, out);
  }
}

// Round 11
// 119.344 us; speedup vs baseline: 1.7236x; 1.7236x over previous
//
#include <hip/hip_runtime.h>

// ---------------------------------------------------------------------------
// r[b,v] = sum_c (feats[b,c,v] - m[c,v]) / s[c,v] * weights[v,c] + bias[v]
// feats per scale k: GEMM  fmap_k (B*Ck x K=n^2)  @  prf_k^T (K x V)
// Fused epilogue: feats tile * w'[c,v]=weights[v,c]/s[c,v], c-reduced,
// atomicAdd into out (pre-initialized with off[v] = bias - sum m*w').
//
// R10 structure (R8 + T3 2-phase): A staged as raw fp32 via global_load_lds
// into a DOUBLE-BUFFERED 2x32KB swizzled LDS tile, prefetched one step
// ahead (stage t+1 issued before compute t -> HBM latency hidden under
// frag-read+MFMA; ONE __syncthreads per step). B direct-to-registers from
// fragment-ordered bf16 ws tiles. Ragged K-tails handled in-block via a
// pre-converted bf16 image staged into the write buffer.
// ---------------------------------------------------------------------------

typedef float f32x4 __attribute__((ext_vector_type(4)));
typedef f32x4 __attribute__((aligned(4))) f32x4u;
typedef __bf16 bf16x4 __attribute__((ext_vector_type(4)));
typedef __bf16 bf16x8 __attribute__((ext_vector_type(8)));

#define TILE_E 8192              // elems per [128x64] tile
#define V_DIM 512
#define C_TOT 960
#define B_DIM 128

#define NBT 268                  // B tiles: 4 col-groups x (49+13+4+1)
#define NRA 896                  // ragged-A images: 128(s1)+256(s2)+512(s3)
#define PREP_WP 1920
#define PREP_OFF 512
#define PREP_BLKS (NBT + NRA + PREP_WP + PREP_OFF)

#define GEMM_BLKS 4608           // 1024(s0)+512(s1)+1024(s2)+2048(s3) = 8*576

// workspace layout (bytes): [wp][bt][ra]
#define WP_BYTES 1966080L
#define BT_BYTES ((long)NBT * TILE_E * 2)   // 4,390,912
#define RA_BYTES ((long)NRA * TILE_E * 2)   // 14,680,064
#define WS_NEED  (WP_BYTES + BT_BYTES + RA_BYTES)

static __device__ __forceinline__ bf16x8 cvt8(f32x4 lo, f32x4 hi) {
  return bf16x8{(__bf16)lo[0], (__bf16)lo[1], (__bf16)lo[2], (__bf16)lo[3],
                (__bf16)hi[0], (__bf16)hi[1], (__bf16)hi[2], (__bf16)hi[3]};
}

// T2 XOR-swizzle, 16B granularity, inside a [128][64]-elem bf16 tile
static __device__ __forceinline__ int swz_idx(int row, int k) {
  return row * 64 + (((k >> 3) ^ (row & 7)) << 3) + (k & 7);
}

// ---------------------------------------------------------------------------
// Main GEMM: one launch, all scales. Requires workspace images.
// ---------------------------------------------------------------------------
__global__ __launch_bounds__(256, 2)
void gemm_main(const float* __restrict__ f0, const float* __restrict__ f1,
               const float* __restrict__ f2, const float* __restrict__ f3,
               const __bf16* __restrict__ bt,   // fragment-ordered B tiles
               const __bf16* __restrict__ ra,   // ragged-A bf16 swz images
               const float* __restrict__ wp,    // [C_TOT, V]
               float* __restrict__ out)         // [B, V]
{
  __shared__ float lds[2 * TILE_E];   // 64 KB: double-buffered fp32 A tile

  const int tid  = threadIdx.x;
  const int lane = tid & 63;
  const int wid  = tid >> 6;
  const int wm   = wid >> 1;
  const int wn   = wid & 1;

  // bijective quad-preserving XCD swizzle (4608 = 8*576): 4 N-siblings of
  // one A-panel land on the same XCD's L2; LPT order (long blocks first).
  const int bid   = blockIdx.x;
  const int sslot = bid >> 3;
  const int xcd   = bid & 7;
  const int w     = (((sslot >> 2) << 3) + xcd) * 4 + (sslot & 3);

  const float* fmap;
  int K, nst, bbase, Ck, Coff, y, bn_g, s0k, nfull;
  long raidx = -1;
  if (w < 1024) {          // scale0: 49 full steps, split-K x4
    fmap = f0; K = 3136; nst = 49; bbase = 0; Ck = 64; Coff = 0;
    bn_g = w & 3; y = (w >> 2) & 63;
    const int z = w >> 8;
    s0k = z * 12; nfull = (z == 3) ? 13 : 12;
  } else if (w < 1536) {   // scale1: 12 full + 1 ragged
    const int l = w - 1024;
    fmap = f1; K = 784; nst = 13; bbase = 196; Ck = 128; Coff = 64;
    bn_g = l & 3; y = l >> 2; s0k = 0; nfull = 12; raidx = y;
  } else if (w < 2560) {   // scale2: 3 full + 1 ragged
    const int l = w - 1536;
    fmap = f2; K = 196; nst = 4; bbase = 248; Ck = 256; Coff = 192;
    bn_g = l & 3; y = l >> 2; s0k = 0; nfull = 3; raidx = 128 + y;
  } else {                 // scale3: ragged only
    const int l = w - 2560;
    fmap = f3; K = 49; nst = 1; bbase = 264; Ck = 512; Coff = 448;
    bn_g = l & 3; y = l >> 2; s0k = 0; nfull = 0; raidx = 384 + y;
  }
  const long bm = (long)y * 128;
  const int  bn = bn_g * 128;
  const bool tail = (raidx >= 0);

  f32x4 acc[4][4];
#pragma unroll
  for (int i = 0; i < 4; ++i)
#pragma unroll
    for (int j = 0; j < 4; ++j)
      acc[i][j] = f32x4{0.f, 0.f, 0.f, 0.f};

  const __bf16* btbase = bt + (long)(bbase + bn_g * nst) * TILE_E;

  // stage raw fp32 A tile of step ks into lds[off..]: inverse-swizzled
  // per-lane source, linear 16B/lane dest (8 x 1KB gl_lds per wave)
  auto stage_a32 = [&](int off, int ks) {
    const float* ab = fmap + bm * (long)K + (long)ks * 64;
#pragma unroll
    for (int i = 0; i < 8; ++i) {
      const int seg = wid * 8 + i;
      const int cc  = seg * 64 + lane;       // dest 16B-chunk 0..2047
      const int row = cc >> 4;
      const int q4  = (cc & 15) ^ (row & 7); // source 4-float chunk
      __builtin_amdgcn_global_load_lds(
          (const __attribute__((address_space(1))) void*)(ab + (long)row * K + q4 * 4),
          (__attribute__((address_space(3))) void*)(&lds[off + seg * 256]),
          16, 0, 0);
    }
  };
  // stage the ragged-step bf16 image (16KB) into lds[off..]
  auto stage_a16 = [&](int off) {
    const __bf16* asrc = ra + raidx * TILE_E;
    __bf16* dst = (__bf16*)&lds[off];
#pragma unroll
    for (int i = 0; i < 4; ++i) {
      const int seg = wid * 4 + i;
      __builtin_amdgcn_global_load_lds(
          (const __attribute__((address_space(1))) void*)(asrc + seg * 512 + lane * 8),
          (__attribute__((address_space(3))) void*)(&dst[seg * 512]),
          16, 0, 0);
    }
  };
  // B fragments of step ks -> registers (frag-ordered, zero-padded tiles)
  auto load_b = [&](int ks, bf16x8* br) {
    const __bf16* tbp = btbase + (long)ks * TILE_E;
#pragma unroll
    for (int j = 0; j < 4; ++j)
#pragma unroll
      for (int kc = 0; kc < 2; ++kc)
        br[j * 2 + kc] = *(const bf16x8*)(
            tbp + ((((wn * 4 + j) * 2 + kc) << 6) + lane) * 8);
  };

  // ---- prologue: fill buffer 0
  if (nfull > 0) stage_a32(0, s0k);
  else if (tail) stage_a16(0);
  __syncthreads();

  // ---- main loop: ONE barrier per step; stage t+1 overlaps compute t
  int p = 0;
  for (int t = 0; t < nfull; ++t) {
    const int ks = s0k + t;
    const int ro = p * TILE_E;          // read buffer
    const int wo = (p ^ 1) * TILE_E;    // write buffer

    bf16x8 breg[8];
    load_b(ks, breg);                   // issued FIRST: breg waits leave the
    if (t + 1 < nfull)      stage_a32(wo, ks + 1);   // stage loads in flight
    else if (tail)          stage_a16(wo);

    __builtin_amdgcn_s_setprio(1);
#pragma unroll
    for (int kc = 0; kc < 2; ++kc) {
      const int q4a = kc * 8 + ((lane >> 4) << 1);
      bf16x8 af[4];
#pragma unroll
      for (int i = 0; i < 4; ++i) {
        const int r = wm * 64 + i * 16 + (lane & 15);
        const f32x4 fa = *(const f32x4*)&lds[ro + r * 64 + ((q4a ^ (r & 7)) << 2)];
        const f32x4 fb = *(const f32x4*)&lds[ro + r * 64 + (((q4a + 1) ^ (r & 7)) << 2)];
        af[i] = cvt8(fa, fb);
      }
#pragma unroll
      for (int i = 0; i < 4; ++i)
#pragma unroll
        for (int j = 0; j < 4; ++j)
          acc[i][j] = __builtin_amdgcn_mfma_f32_16x16x32_bf16(
              af[i], breg[j * 2 + kc], acc[i][j], 0, 0, 0);
    }
    __builtin_amdgcn_s_setprio(0);

    __syncthreads();   // drains stage vmcnt (issued ~a full phase ago)
    p ^= 1;
  }

  // ---- ragged tail step: bf16-image fragments from current read buffer
  if (tail) {
    const __bf16* lb = (const __bf16*)&lds[p * TILE_E];
    bf16x8 breg[8];
    load_b(nfull, breg);                 // ks = kfull (zero-padded B tile)
    __builtin_amdgcn_s_setprio(1);
#pragma unroll
    for (int kc = 0; kc < 2; ++kc) {
      const int cx = kc * 4 + (lane >> 4);
      bf16x8 af[4];
#pragma unroll
      for (int i = 0; i < 4; ++i) {
        const int r = wm * 64 + i * 16 + (lane & 15);
        af[i] = *(const bf16x8*)&lb[r * 64 + ((cx ^ (r & 7)) << 3)];
      }
#pragma unroll
      for (int i = 0; i < 4; ++i)
#pragma unroll
        for (int j = 0; j < 4; ++j)
          acc[i][j] = __builtin_amdgcn_mfma_f32_16x16x32_bf16(
              af[i], breg[j * 2 + kc], acc[i][j], 0, 0, 0);
    }
    __builtin_amdgcn_s_setprio(0);
  }

  // ---- epilogue: per-wave 64x64 feats sub-tile, c-reduce, atomicAdd.
  // C/D layout: frag row = (lane>>4)*4 + reg, frag col = lane&15   [m89]
  const long mbase = bm + wm * 64;
  const int  bidx  = (int)(mbase / Ck);
  const int  cbase = (int)(mbase % Ck) + Coff;
  const int  lrow  = ((lane >> 4) << 2);
  const int  lcol  = lane & 15;

#pragma unroll
  for (int j = 0; j < 4; ++j) {
    const int v = bn + wn * 64 + j * 16 + lcol;
    float s = 0.f;
#pragma unroll
    for (int i = 0; i < 4; ++i) {
      const int cg = cbase + i * 16 + lrow;
#pragma unroll
      for (int r = 0; r < 4; ++r)
        s += acc[i][j][r] * wp[(long)(cg + r) * V_DIM + v];
    }
    s += __shfl_xor(s, 16);
    s += __shfl_xor(s, 32);
    if (lane < 16)
      atomicAdd(&out[(long)bidx * V_DIM + v], s);
  }
}

// ---------------------------------------------------------------------------
// Ragged-A image convert: img[swz_idx(row,k)] = src[rbase+row, ks*64+k],
// zero-padded past K.
// ---------------------------------------------------------------------------
static __device__ __forceinline__ void conv_tile(const float* __restrict__ src,
                                                 int K, long rbase, int ks,
                                                 __bf16* __restrict__ dst, int tid)
{
#pragma unroll
  for (int it = 0; it < 4; ++it) {
    const int u   = tid + it * 256;
    const int row = u >> 3;
    const int q8  = u & 7;
    const int k   = ((q8 ^ (row & 7)) << 3);
    const long gk = (long)ks * 64 + k;
    const float* sp = src + (rbase + row) * (long)K + gk;
    bf16x8 h;
    if (gk + 8 <= K) {
      h = cvt8(*(const f32x4u*)sp, *(const f32x4u*)(sp + 4));
    } else {
#pragma unroll
      for (int e = 0; e < 8; ++e)
        h[e] = (__bf16)((gk + e < K) ? sp[e] : 0.f);
    }
    *(bf16x8*)&dst[(long)row * 64 + q8 * 8] = h;
  }
}

// ---------------------------------------------------------------------------
// One prep launch: [0,268) B frag-ordered tiles; [268,1164) ragged-A images;
// then w'; then out init with the constant term.
// B tile layout: dst[((fj*2+kc)*64 + l)*8 + e] =
//   B[g*128 + fj*16 + (l&15), ks*64 + kc*32 + ((l>>4)<<3) + e]  (0-padded)
// ---------------------------------------------------------------------------
__global__ void prep_all(const float* __restrict__ f1, const float* __restrict__ f2,
                         const float* __restrict__ f3,
                         const float* __restrict__ p0, const float* __restrict__ p1,
                         const float* __restrict__ p2, const float* __restrict__ p3,
                         const float* __restrict__ weights,
                         const float* __restrict__ bias,
                         const float* __restrict__ fm,
                         const float* __restrict__ fs,
                         float* __restrict__ wp,      // may be null
                         __bf16* __restrict__ bt,     // may be null
                         __bf16* __restrict__ ra,     // may be null
                         float* __restrict__ out)
{
  __shared__ float red[4];
  const int blk = blockIdx.x;
  const int tid = threadIdx.x;

  if (blk < NBT) {
    if (!bt) return;
    int t = blk; const float* src; int K, g, ks;
    if (t < 196)      { src = p0; K = 3136; g = t / 49; ks = t % 49; }
    else if (t < 248) { t -= 196; src = p1; K = 784; g = t / 13; ks = t % 13; }
    else if (t < 264) { t -= 248; src = p2; K = 196; g = t / 4;  ks = t % 4; }
    else              { t -= 264; src = p3; K = 49;  g = t;      ks = 0; }
    __bf16* dst = bt + (long)blk * TILE_E;
#pragma unroll
    for (int it = 0; it < 4; ++it) {
      const int c2 = tid + it * 256;
      const int fj = c2 >> 7;
      const int kc = (c2 >> 6) & 1;
      const int l  = c2 & 63;
      const int row  = g * 128 + fj * 16 + (l & 15);
      const int kcol = ks * 64 + kc * 32 + ((l >> 4) << 3);
      const float* sp = src + (long)row * K + kcol;
      bf16x8 h;
      if (kcol + 8 <= K) {
        h = cvt8(*(const f32x4u*)sp, *(const f32x4u*)(sp + 4));
      } else {
#pragma unroll
        for (int e = 0; e < 8; ++e)
          h[e] = (__bf16)((kcol + e < K) ? sp[e] : 0.f);
      }
      *(bf16x8*)&dst[(long)c2 * 8] = h;
    }
  } else if (blk < NBT + NRA) {
    if (!ra) return;
    const int t = blk - NBT; const float* src; int K, ks; long rbase;
    if (t < 128)      { src = f1; K = 784; ks = 12; rbase = (long)t * 128; }
    else if (t < 384) { src = f2; K = 196; ks = 3;  rbase = (long)(t - 128) * 128; }
    else              { src = f3; K = 49;  ks = 0;  rbase = (long)(t - 384) * 128; }
    conv_tile(src, K, rbase, ks, ra + (long)t * TILE_E, tid);
  } else if (blk < NBT + NRA + PREP_WP) {
    if (!wp) return;
    const int idx = (blk - NBT - NRA) * 256 + tid;   // exactly 960*512
    const int c = idx >> 9;
    const int v = idx & (V_DIM - 1);
    wp[idx] = weights[(long)v * C_TOT + c] / fs[idx];
  } else {
    const int v = blk - (NBT + NRA + PREP_WP);       // 0..511
    float s = 0.f;
    for (int c = tid; c < C_TOT; c += 256) {
      const long i = (long)c * V_DIM + v;
      s += fm[i] * weights[(long)v * C_TOT + c] / fs[i];
    }
#pragma unroll
    for (int o = 32; o; o >>= 1) s += __shfl_down(s, o);
    if ((tid & 63) == 0) red[tid >> 6] = s;
    __syncthreads();
    if (tid < B_DIM) {
      const float off = bias[v] - (red[0] + red[1] + red[2] + red[3]);
      out[(long)tid * V_DIM + v] = off;
    }
  }
}

// ---------------------------------------------------------------------------
// Fallback GEMM (ws too small): inline fp32 staging of both operands.
// ---------------------------------------------------------------------------
__global__ __launch_bounds__(256, 3)
void gemm_fb(const float* __restrict__ fmap, const float* __restrict__ prf,
             const float* __restrict__ weights, const float* __restrict__ fs,
             const float* __restrict__ wp, float* __restrict__ out,
             int Ck, int K, int Coff, int nsteps, int kchunks)
{
  __shared__ __bf16 lds_a[TILE_E];
  __shared__ __bf16 lds_b[TILE_E];
  const int tid = threadIdx.x, lane = tid & 63, wid = tid >> 6;
  const int wm = wid >> 1, wn = wid & 1;
  const long bm = (long)blockIdx.y * 128;
  const int bn = blockIdx.x * 128;
  const int z = blockIdx.z, qb = nsteps / kchunks, rb = nsteps % kchunks;
  const int s0 = z * qb + (z < rb ? z : rb);
  const int send = s0 + qb + (z < rb ? 1 : 0);

  f32x4 acc[4][4];
#pragma unroll
  for (int i = 0; i < 4; ++i)
#pragma unroll
    for (int j = 0; j < 4; ++j) acc[i][j] = f32x4{0.f, 0.f, 0.f, 0.f};

  for (int ks = s0; ks < send; ++ks) {
    __syncthreads();
#pragma unroll
    for (int i = 0; i < 8; ++i) {
      const int c = tid + i * 256, row = c >> 4, k0 = (c & 15) << 2;
      const long gk = (long)ks * 64 + k0;
      const float* ap = fmap + (bm + row) * (long)K + gk;
      const float* bp = prf + (long)(bn + row) * K + gk;
      float a[4], b[4];
#pragma unroll
      for (int e = 0; e < 4; ++e) {
        a[e] = (gk + e < K) ? ap[e] : 0.f;
        b[e] = (gk + e < K) ? bp[e] : 0.f;
      }
      bf16x4 ha = {(__bf16)a[0], (__bf16)a[1], (__bf16)a[2], (__bf16)a[3]};
      bf16x4 hb = {(__bf16)b[0], (__bf16)b[1], (__bf16)b[2], (__bf16)b[3]};
      *(bf16x4*)&lds_a[swz_idx(row, k0)] = ha;
      *(bf16x4*)&lds_b[swz_idx(row, k0)] = hb;
    }
    __syncthreads();
#pragma unroll
    for (int kc = 0; kc < 2; ++kc) {
      const int cx = kc * 4 + (lane >> 4);
      bf16x8 af[4], bfr[4];
#pragma unroll
      for (int i = 0; i < 4; ++i) {
        const int r = wm * 64 + i * 16 + (lane & 15);
        af[i] = *(const bf16x8*)&lds_a[r * 64 + ((cx ^ (r & 7)) << 3)];
      }
#pragma unroll
      for (int j = 0; j < 4; ++j) {
        const int r = wn * 64 + j * 16 + (lane & 15);
        bfr[j] = *(const bf16x8*)&lds_b[r * 64 + ((cx ^ (r & 7)) << 3)];
      }
#pragma unroll
      for (int i = 0; i < 4; ++i)
#pragma unroll
        for (int j = 0; j < 4; ++j)
          acc[i][j] = __builtin_amdgcn_mfma_f32_16x16x32_bf16(af[i], bfr[j],
                                                              acc[i][j], 0, 0, 0);
    }
  }

  const long mbase = bm + wm * 64;
  const int bidx = (int)(mbase / Ck);
  const int cbase = (int)(mbase % Ck) + Coff;
  const int lrow = ((lane >> 4) << 2), lcol = lane & 15;
#pragma unroll
  for (int j = 0; j < 4; ++j) {
    const int v = bn + wn * 64 + j * 16 + lcol;
    float s = 0.f;
#pragma unroll
    for (int i = 0; i < 4; ++i) {
      const int cg = cbase + i * 16 + lrow;
#pragma unroll
      for (int r = 0; r < 4; ++r) {
        const float wf = wp ? wp[(long)(cg + r) * V_DIM + v]
                            : weights[(long)v * C_TOT + cg + r]
                              / fs[(long)(cg + r) * V_DIM + v];
        s += acc[i][j][r] * wf;
      }
    }
    s += __shfl_xor(s, 16);
    s += __shfl_xor(s, 32);
    if (lane < 16) atomicAdd(&out[(long)bidx * V_DIM + v], s);
  }
}

extern "C" void kernel_launch(void* const* d_in, const int* in_sizes, int n_in,
                              void* d_out, int out_size, void* d_ws, size_t ws_size,
                              hipStream_t stream)
{
  const float* fmap0   = (const float*)d_in[0];
  const float* prf0    = (const float*)d_in[1];
  const float* fmap1   = (const float*)d_in[2];
  const float* prf1    = (const float*)d_in[3];
  const float* fmap2   = (const float*)d_in[4];
  const float* prf2    = (const float*)d_in[5];
  const float* fmap3   = (const float*)d_in[6];
  const float* prf3    = (const float*)d_in[7];
  const float* weights = (const float*)d_in[8];
  const float* bias    = (const float*)d_in[9];
  const float* fm      = (const float*)d_in[10];
  const float* fs      = (const float*)d_in[11];
  float* out = (float*)d_out;

  const bool has_wp = ws_size >= (size_t)WP_BYTES;
  const bool has_ws = ws_size >= (size_t)WS_NEED;
  float*  wp = has_wp ? (float*)d_ws : nullptr;
  __bf16* bt = has_ws ? (__bf16*)((char*)d_ws + WP_BYTES) : nullptr;
  __bf16* ra = has_ws ? (__bf16*)((char*)d_ws + WP_BYTES + BT_BYTES) : nullptr;

  // 1) prep: B frag tiles + ragged-A images + w' + out init
  prep_all<<<dim3(PREP_BLKS), dim3(256), 0, stream>>>(
      fmap1, fmap2, fmap3, prf0, prf1, prf2, prf3,
      weights, bias, fm, fs, wp, bt, ra, out);

  // 2) GEMM
  if (has_ws) {
    gemm_main<<<dim3(GEMM_BLKS), dim3(256), 0, stream>>>(
        fmap0, fmap1, fmap2, fmap3, bt, ra, wp, out);
  } else {
    struct Scale { const float* fmap; const float* prf; int Ck, K, Coff, nst, kch; };
    const Scale sc[4] = {
      {fmap0, prf0,  64, 3136,   0, 49, 4},
      {fmap1, prf1, 128,  784,  64, 13, 2},
      {fmap2, prf2, 256,  196, 192,  4, 1},
      {fmap3, prf3, 512,   49, 448,  1, 1},
    };
    for (int k = 0; k < 4; ++k) {
      dim3 grid(4, B_DIM * sc[k].Ck / 128, sc[k].kch);
      gemm_fb<<<grid, dim3(256), 0, stream>>>(
          sc[k].fmap, sc[k].prf, weights, fs, wp, out,
          sc[k].Ck, sc[k].K, sc[k].Coff, sc[k].nst, sc[k].kch);
    }
  }
}